// Round 1
// baseline (483.925 us; speedup 1.0000x reference)
//
#include <hip/hip_runtime.h>

#define NN 20000
#define EE 320000
#define BB 4
#define KK 32
#define DD 32
#define DRR 40
#define TT 10

static constexpr float VTH = 2.0f;

// ---------------- prep: query gather + w_rel = query @ relw_W + b ----------------
__global__ __launch_bounds__(256) void prep_kernel(
    const int* __restrict__ r_index, const float* __restrict__ query_emb,
    const float* __restrict__ relw_W, const float* __restrict__ relw_b,
    float* __restrict__ w_rel, float* __restrict__ query)
{
    int idx = blockIdx.x * 256 + threadIdx.x;        // 0..5119
    int b = idx / (DRR * DD);
    int o = idx % (DRR * DD);                        // typ*32 + d
    const float* q = query_emb + r_index[b] * DD;
    float acc = relw_b[o];
    for (int i = 0; i < DD; ++i)
        acc += q[i] * relw_W[i * (DRR * DD) + o];
    w_rel[idx] = acc;
    if (idx < BB * DD)
        query[idx] = query_emb[r_index[idx >> 5] * DD + (idx & 31)];
}

// ---------------- zero the per-node counter ----------------
__global__ __launch_bounds__(256) void zero_cnt_kernel(int* __restrict__ cnt)
{
    int i = blockIdx.x * 256 + threadIdx.x;
    if (i < NN) cnt[i] = 0;
}

// ---------------- init LIF state + s0 bitmask ----------------
__global__ __launch_bounds__(256) void init_kernel(
    const int* __restrict__ h_index, const float* __restrict__ query,
    float* __restrict__ v, float* __restrict__ c, unsigned* __restrict__ sb0)
{
    int idx = blockIdx.x * 256 + threadIdx.x;        // N*B*D
    int d = idx & 31;
    int g = idx >> 5;                                // n*B + b
    int b = g & (BB - 1);
    int n = g >> 2;
    float boundary = 0.0f;
    if (n == h_index[b])
        boundary = query[b * DD + d] * (VTH * 0.5f) + (VTH * 0.5f);
    int s = (boundary - VTH >= 0.0f) ? 1 : 0;
    v[idx] = boundary * (1.0f - (float)s);
    c[idx] = 0.0f;
    unsigned long long m = __ballot(s);
    int l = threadIdx.x & 63;
    if (l == 0)       sb0[g] = (unsigned)m;
    else if (l == 32) sb0[g] = (unsigned)(m >> 32);
}

// ---------------- CSR build ----------------
__global__ __launch_bounds__(256) void hist_kernel(const int* __restrict__ edge_dst,
                                                   int* __restrict__ cnt)
{
    int e = blockIdx.x * 256 + threadIdx.x;
    if (e < EE) atomicAdd(&cnt[edge_dst[e]], 1);
}

__global__ __launch_bounds__(1024) void scan_kernel(int* __restrict__ cnt,
                                                    int* __restrict__ row_ptr)
{
    __shared__ int buf[1024];
    __shared__ int run_s;
    int tid = threadIdx.x;
    if (tid == 0) run_s = 0;
    __syncthreads();
    for (int base = 0; base < NN; base += 1024) {
        int i = base + tid;
        int x = (i < NN) ? cnt[i] : 0;
        if (i < NN) cnt[i] = 0;                      // reset for scatter pass
        buf[tid] = x;
        __syncthreads();
        for (int off = 1; off < 1024; off <<= 1) {
            int y = (tid >= off) ? buf[tid - off] : 0;
            __syncthreads();
            buf[tid] += y;
            __syncthreads();
        }
        int excl = buf[tid] - x + run_s;
        if (i < NN) row_ptr[i] = excl;
        __syncthreads();
        if (tid == 0) run_s += buf[1023];
        __syncthreads();
    }
    if (tid == 0) row_ptr[NN] = run_s;
}

__global__ __launch_bounds__(256) void scatter_kernel(
    const int* __restrict__ edge_src, const int* __restrict__ edge_dst,
    const int* __restrict__ edge_type, const int* __restrict__ row_ptr,
    int* __restrict__ cnt, unsigned* __restrict__ col)
{
    int e = blockIdx.x * 256 + threadIdx.x;
    if (e < EE) {
        int dn = edge_dst[e];
        int pos = row_ptr[dn] + atomicAdd(&cnt[dn], 1);
        col[pos] = (unsigned)edge_src[e] | ((unsigned)edge_type[e] << 16);
    }
}

// ---------------- one LIF time step ----------------
__global__ __launch_bounds__(256) void step_kernel(
    const int* __restrict__ row_ptr, const unsigned* __restrict__ col,
    const unsigned* __restrict__ sb_cur, unsigned* __restrict__ sb_nxt,
    const float* __restrict__ w_rel, const float* __restrict__ lin_W,
    const float* __restrict__ lin_b, float* __restrict__ v, float* __restrict__ c)
{
    __shared__ float lds_w[BB * DRR * DD];   // 5120 f32: w_rel[b][typ][d]
    __shared__ float lds_WT[DD * DD];        // lin_W transposed: [j][d]
    __shared__ float lds_b[DD];
    int tid = threadIdx.x;
    for (int i = tid; i < BB * DRR * DD; i += 256) lds_w[i] = w_rel[i];
    for (int i = tid; i < DD * DD; i += 256)
        lds_WT[(i & 31) * DD + (i >> 5)] = lin_W[i];
    if (tid < DD) lds_b[tid] = lin_b[tid];
    __syncthreads();

    int n = blockIdx.x * 8 + (tid >> 5);
    int d = tid & 31;
    float agg0 = 0.f, agg1 = 0.f, agg2 = 0.f, agg3 = 0.f;
    int e0 = row_ptr[n], e1 = row_ptr[n + 1];
    for (int e = e0; e < e1; ++e) {
        unsigned u = col[e];
        int src = u & 0xFFFF;
        int typ = (int)(u >> 16);
        uint4 sb = *(const uint4*)(sb_cur + src * BB);
        const float* wp = &lds_w[typ * DD + d];
        agg0 += ((sb.x >> d) & 1) ? wp[0 * DRR * DD] : 0.0f;
        agg1 += ((sb.y >> d) & 1) ? wp[1 * DRR * DD] : 0.0f;
        agg2 += ((sb.z >> d) & 1) ? wp[2 * DRR * DD] : 0.0f;
        agg3 += ((sb.w >> d) & 1) ? wp[3 * DRR * DD] : 0.0f;
    }

    const float decay = 0.7788007831f;       // exp(-1/tau), tau=4
    int l = tid & 63;
    float aggs[4] = {agg0, agg1, agg2, agg3};
    #pragma unroll
    for (int b = 0; b < BB; ++b) {
        float x = lds_b[d];
        #pragma unroll
        for (int j = 0; j < DD; ++j)
            x += lds_WT[j * DD + d] * __shfl(aggs[b], j, 32);
        int base = (n * BB + b) * DD + d;
        float cn = c[base] * decay + x;
        float vn = v[base] * decay + cn;
        int s = (vn - VTH >= 0.0f) ? 1 : 0;
        vn = s ? 0.0f : vn;
        c[base] = cn;
        v[base] = vn;
        unsigned long long m = __ballot(s);
        if (l == 0)       sb_nxt[n * BB + b] = (unsigned)m;
        else if (l == 32) sb_nxt[n * BB + b] = (unsigned)(m >> 32);
    }
}

// ---------------- temporal-kernel accumulation at target slots ----------------
__global__ __launch_bounds__(256) void enc_acc_kernel(
    const int* __restrict__ t_index, const unsigned* __restrict__ sb,
    float* __restrict__ enc, int t, int init)
{
    int idx = blockIdx.x * 256 + threadIdx.x;   // B*K*D = 4096
    int d = idx & 31;
    int row = idx >> 5;                         // b*K + k
    int b = row >> 5;                           // K == 32
    int node = t_index[row];
    float r = 0.95f;
    float n_scale = (1.0f - powf(r, (float)TT)) / (1.0f - r);
    float kt = powf(r, (float)t) / n_scale;
    float bit = (float)((sb[node * BB + b] >> d) & 1);
    float val = kt * bit;
    if (init) enc[idx] = val;
    else      enc[idx] += val;
}

// ---------------- final MLP scorer ----------------
__global__ __launch_bounds__(128) void final_kernel(
    const float* __restrict__ enc, const float* __restrict__ query,
    const float* __restrict__ W1, const float* __restrict__ b1,
    const float* __restrict__ W2, const float* __restrict__ b2,
    float* __restrict__ out)
{
    int row = threadIdx.x;                      // 0..127 = b*K + k
    int b = row >> 5;
    float feat[2 * DD];
    #pragma unroll
    for (int i = 0; i < DD; ++i) feat[i] = enc[row * DD + i];
    #pragma unroll
    for (int i = 0; i < DD; ++i) feat[DD + i] = query[b * DD + i];
    float acc = b2[0];
    for (int j = 0; j < 2 * DD; ++j) {
        float h = b1[j];
        #pragma unroll
        for (int i = 0; i < 2 * DD; ++i) h += feat[i] * W1[j * 2 * DD + i];
        h = fmaxf(h, 0.0f);
        acc += W2[j] * h;
    }
    out[row] = acc;
}

extern "C" void kernel_launch(void* const* d_in, const int* in_sizes, int n_in,
                              void* d_out, int out_size, void* d_ws, size_t ws_size,
                              hipStream_t stream)
{
    const int*   edge_src  = (const int*)d_in[0];
    const int*   edge_dst  = (const int*)d_in[1];
    const int*   edge_type = (const int*)d_in[2];
    const int*   h_index   = (const int*)d_in[3];
    const int*   t_index   = (const int*)d_in[4];
    const int*   r_index   = (const int*)d_in[5];
    const float* query_emb = (const float*)d_in[6];
    const float* relw_W    = (const float*)d_in[7];
    const float* relw_b    = (const float*)d_in[8];
    const float* lin_W     = (const float*)d_in[9];
    const float* lin_b     = (const float*)d_in[10];
    const float* mlp_W1    = (const float*)d_in[11];
    const float* mlp_b1    = (const float*)d_in[12];
    const float* mlp_W2    = (const float*)d_in[13];
    const float* mlp_b2    = (const float*)d_in[14];
    float* out = (float*)d_out;

    // workspace layout (4-byte units)
    float*    v       = (float*)d_ws;                 // N*B*D = 2,560,000
    float*    c       = v + NN * BB * DD;             // 2,560,000
    unsigned* sb0     = (unsigned*)(c + NN * BB * DD);// 80,000
    unsigned* sb1     = sb0 + NN * BB;                // 80,000
    float*    w_rel   = (float*)(sb1 + NN * BB);      // 5,120
    float*    query   = w_rel + BB * DRR * DD;        // 128
    float*    enc     = query + BB * DD;              // 4,096
    int*      row_ptr = (int*)(enc + BB * KK * DD);   // 20,016 (padded)
    int*      cnt     = row_ptr + 20016;              // 20,000
    unsigned* col     = (unsigned*)(cnt + NN);        // 320,000

    prep_kernel<<<(BB * DRR * DD) / 256, 256, 0, stream>>>(
        r_index, query_emb, relw_W, relw_b, w_rel, query);
    zero_cnt_kernel<<<(NN + 255) / 256, 256, 0, stream>>>(cnt);
    init_kernel<<<(NN * BB * DD) / 256, 256, 0, stream>>>(h_index, query, v, c, sb0);
    hist_kernel<<<(EE + 255) / 256, 256, 0, stream>>>(edge_dst, cnt);
    scan_kernel<<<1, 1024, 0, stream>>>(cnt, row_ptr);
    scatter_kernel<<<(EE + 255) / 256, 256, 0, stream>>>(
        edge_src, edge_dst, edge_type, row_ptr, cnt, col);
    enc_acc_kernel<<<(BB * KK * DD) / 256, 256, 0, stream>>>(t_index, sb0, enc, 0, 1);

    unsigned* bufs[2] = {sb0, sb1};
    for (int t = 1; t < TT; ++t) {
        step_kernel<<<NN / 8, 256, 0, stream>>>(
            row_ptr, col, bufs[(t - 1) & 1], bufs[t & 1], w_rel, lin_W, lin_b, v, c);
        enc_acc_kernel<<<(BB * KK * DD) / 256, 256, 0, stream>>>(
            t_index, bufs[t & 1], enc, t, 0);
    }
    final_kernel<<<1, 128, 0, stream>>>(enc, query, mlp_W1, mlp_b1, mlp_W2, mlp_b2, out);
}

// Round 2
// 358.264 us; speedup vs baseline: 1.3508x; 1.3508x over previous
//
#include <hip/hip_runtime.h>

#define NN 20000
#define EE 320000
#define BB 4
#define KK 32
#define DD 32
#define DRR 40
#define TT 10
#define NPB 16          // nodes per block (one 32-lane group per node)
#define THREADS 512

static constexpr float VTH = 2.0f;
static constexpr float DECAY = 0.7788007831f;   // exp(-1/4)

// ---------------- prep: query gather + w_rel = query @ relw_W + b ----------------
// w_rel stored as [typ][d][b] so step kernel reads one float4 per (typ,d).
__global__ __launch_bounds__(256) void prep_kernel(
    const int* __restrict__ r_index, const float* __restrict__ query_emb,
    const float* __restrict__ relw_W, const float* __restrict__ relw_b,
    float* __restrict__ w_rel, float* __restrict__ query)
{
    int idx = blockIdx.x * 256 + threadIdx.x;        // 0..5119
    int b = idx / (DRR * DD);
    int o = idx % (DRR * DD);                        // typ*32 + d
    int typ = o >> 5, d = o & 31;
    const float* q = query_emb + r_index[b] * DD;
    float acc = relw_b[o];
    for (int i = 0; i < DD; ++i)
        acc += q[i] * relw_W[i * (DRR * DD) + o];
    w_rel[typ * (DD * BB) + d * BB + b] = acc;
    if (idx < BB * DD)
        query[idx] = query_emb[r_index[idx >> 5] * DD + (idx & 31)];
}

__global__ __launch_bounds__(256) void zero_cnt_kernel(int* __restrict__ cnt)
{
    int i = blockIdx.x * 256 + threadIdx.x;
    if (i < NN) cnt[i] = 0;
}

// ---------------- init LIF state (layout [n][d][b]) + zero spike masks ----------------
__global__ __launch_bounds__(256) void init_kernel(
    const int* __restrict__ h_index, const float* __restrict__ query,
    float* __restrict__ v, float* __restrict__ c, unsigned* __restrict__ sb0)
{
    int idx = blockIdx.x * 256 + threadIdx.x;        // N*D*B
    int n = idx >> 7;
    int r = idx & 127;
    int d = r >> 2;
    int b = r & 3;
    float boundary = 0.0f;
    if (n == h_index[b])
        boundary = query[b * DD + d] * (VTH * 0.5f) + (VTH * 0.5f);
    float s = (boundary - VTH >= 0.0f) ? 1.0f : 0.0f;
    v[idx] = boundary * (1.0f - s);
    c[idx] = 0.0f;
    if (idx < NN * BB) sb0[idx] = 0;
}

// seed spike bits of the 4 head nodes
__global__ __launch_bounds__(128) void seed_kernel(
    const int* __restrict__ h_index, const float* __restrict__ query,
    unsigned* __restrict__ sb0)
{
    int tid = threadIdx.x;                           // 0..127
    int b = tid >> 5, d = tid & 31;
    float boundary = query[b * DD + d] + 1.0f;       // q*(VTH/2)+VTH/2, VTH=2
    int s = (boundary - VTH >= 0.0f) ? 1 : 0;
    unsigned long long m = __ballot(s);
    int l = tid & 63;
    if (l == 0)       sb0[h_index[b] * BB + b] = (unsigned)m;
    else if (l == 32) sb0[h_index[b] * BB + b] = (unsigned)(m >> 32);
}

// ---------------- CSR build ----------------
__global__ __launch_bounds__(256) void hist_kernel(const int* __restrict__ edge_dst,
                                                   int* __restrict__ cnt)
{
    int e = blockIdx.x * 256 + threadIdx.x;
    if (e < EE) atomicAdd(&cnt[edge_dst[e]], 1);
}

__global__ __launch_bounds__(1024) void scan_kernel(int* __restrict__ cnt,
                                                    int* __restrict__ row_ptr)
{
    __shared__ int buf[1024];
    __shared__ int run_s;
    int tid = threadIdx.x;
    if (tid == 0) run_s = 0;
    __syncthreads();
    for (int base = 0; base < NN; base += 1024) {
        int i = base + tid;
        int x = (i < NN) ? cnt[i] : 0;
        if (i < NN) cnt[i] = 0;                      // reset for scatter pass
        buf[tid] = x;
        __syncthreads();
        for (int off = 1; off < 1024; off <<= 1) {
            int y = (tid >= off) ? buf[tid - off] : 0;
            __syncthreads();
            buf[tid] += y;
            __syncthreads();
        }
        int excl = buf[tid] - x + run_s;
        if (i < NN) row_ptr[i] = excl;
        __syncthreads();
        if (tid == 0) run_s += buf[1023];
        __syncthreads();
    }
    if (tid == 0) row_ptr[NN] = run_s;
}

__global__ __launch_bounds__(256) void scatter_kernel(
    const int* __restrict__ edge_src, const int* __restrict__ edge_dst,
    const int* __restrict__ edge_type, const int* __restrict__ row_ptr,
    int* __restrict__ cnt, unsigned* __restrict__ col)
{
    int e = blockIdx.x * 256 + threadIdx.x;
    if (e < EE) {
        int dn = edge_dst[e];
        int pos = row_ptr[dn] + atomicAdd(&cnt[dn], 1);
        col[pos] = (unsigned)edge_src[e] | ((unsigned)edge_type[e] << 16);
    }
}

// ---------------- one LIF time step (batched edge loads, LDS broadcasts) ----------------
__global__ __launch_bounds__(THREADS) void step_kernel(
    const int* __restrict__ row_ptr, const unsigned* __restrict__ col,
    const unsigned* __restrict__ sb_cur, unsigned* __restrict__ sb_nxt,
    const float* __restrict__ w_rel, const float* __restrict__ lin_W,
    const float* __restrict__ lin_b, float* __restrict__ v, float* __restrict__ c,
    const int* __restrict__ t_index, float* __restrict__ enc, float kprev, int init)
{
    __shared__ float4 lds_w[DRR * DD];        // [typ][d] -> float4 over b (20 KB)
    __shared__ unsigned stg_u[NPB][DD];       // staged edge words (2 KB)
    __shared__ uint4 stg_sb[NPB][DD];         // staged source spike words (8 KB)
    __shared__ float lds_agg[NPB][BB][DD];    // agg staging (8 KB)

    int tid = threadIdx.x;
    for (int i = tid; i < DRR * DD; i += THREADS)
        lds_w[i] = *(const float4*)(w_rel + i * 4);
    __syncthreads();

    int d = tid & 31;
    int g = tid >> 5;                          // group 0..15, one node each
    // lin_W row d in registers
    float4 Wr[8];
    #pragma unroll
    for (int q = 0; q < 8; ++q)
        Wr[q] = *(const float4*)(lin_W + d * DD + q * 4);
    float bias = lin_b[d];

    // fused enc accumulation for time t-1 (reads completed sb_cur input)
    if (blockIdx.x == 0) {
        for (int i = tid; i < BB * KK * DD; i += THREADS) {
            int row = i >> 5, dd = i & 31;
            int b = row >> 5;
            int node = t_index[row];
            float bit = (float)((sb_cur[node * BB + b] >> dd) & 1);
            float val = kprev * bit;
            enc[i] = init ? val : (enc[i] + val);
        }
    }

    int n = blockIdx.x * NPB + g;
    int e0 = row_ptr[n], e1 = row_ptr[n + 1];
    float agg0 = 0.f, agg1 = 0.f, agg2 = 0.f, agg3 = 0.f;

    for (int base = e0; base < e1; base += DD) {
        int eidx = base + d;
        unsigned u = 0;
        uint4 sv = make_uint4(0, 0, 0, 0);
        if (eidx < e1) {
            u = col[eidx];
            sv = *(const uint4*)(sb_cur + (u & 0xFFFFu) * BB);
        }
        stg_u[g][d] = u;
        stg_sb[g][d] = sv;
        int ne = min(DD, e1 - base);
        for (int j = 0; j < ne; ++j) {
            unsigned uj = stg_u[g][j];               // broadcast read
            uint4 sj = stg_sb[g][j];                 // broadcast read
            float4 wv = lds_w[(uj >> 16) * DD + d];  // conflict-free b128
            agg0 += ((sj.x >> d) & 1u) ? wv.x : 0.0f;
            agg1 += ((sj.y >> d) & 1u) ? wv.y : 0.0f;
            agg2 += ((sj.z >> d) & 1u) ? wv.z : 0.0f;
            agg3 += ((sj.w >> d) & 1u) ? wv.w : 0.0f;
        }
    }

    // stage agg, then x[b][d] = bias + sum_j agg[b][j] * lin_W[d][j]
    lds_agg[g][0][d] = agg0;
    lds_agg[g][1][d] = agg1;
    lds_agg[g][2][d] = agg2;
    lds_agg[g][3][d] = agg3;

    float4 vv = *(const float4*)(v + n * (DD * BB) + d * 4);  // layout [n][d][b]
    float4 cc = *(const float4*)(c + n * (DD * BB) + d * 4);

    float xs[BB];
    #pragma unroll
    for (int b = 0; b < BB; ++b) {
        float x = bias;
        #pragma unroll
        for (int q = 0; q < 8; ++q) {
            float4 a4 = *(const float4*)&lds_agg[g][b][q * 4];  // broadcast
            x += a4.x * Wr[q].x + a4.y * Wr[q].y + a4.z * Wr[q].z + a4.w * Wr[q].w;
        }
        xs[b] = x;
    }

    float cn, vn;
    cn = cc.x * DECAY + xs[0]; vn = vv.x * DECAY + cn; int s0 = (vn - VTH >= 0.0f); cc.x = cn; vv.x = s0 ? 0.0f : vn;
    cn = cc.y * DECAY + xs[1]; vn = vv.y * DECAY + cn; int s1 = (vn - VTH >= 0.0f); cc.y = cn; vv.y = s1 ? 0.0f : vn;
    cn = cc.z * DECAY + xs[2]; vn = vv.z * DECAY + cn; int s2 = (vn - VTH >= 0.0f); cc.z = cn; vv.z = s2 ? 0.0f : vn;
    cn = cc.w * DECAY + xs[3]; vn = vv.w * DECAY + cn; int s3 = (vn - VTH >= 0.0f); cc.w = cn; vv.w = s3 ? 0.0f : vn;

    *(float4*)(v + n * (DD * BB) + d * 4) = vv;
    *(float4*)(c + n * (DD * BB) + d * 4) = cc;

    unsigned long long m0 = __ballot(s0);
    unsigned long long m1 = __ballot(s1);
    unsigned long long m2 = __ballot(s2);
    unsigned long long m3 = __ballot(s3);
    int l = tid & 63;
    if (l == 0) {
        sb_nxt[n * BB + 0] = (unsigned)m0;
        sb_nxt[n * BB + 1] = (unsigned)m1;
        sb_nxt[n * BB + 2] = (unsigned)m2;
        sb_nxt[n * BB + 3] = (unsigned)m3;
    } else if (l == 32) {
        sb_nxt[n * BB + 0] = (unsigned)(m0 >> 32);
        sb_nxt[n * BB + 1] = (unsigned)(m1 >> 32);
        sb_nxt[n * BB + 2] = (unsigned)(m2 >> 32);
        sb_nxt[n * BB + 3] = (unsigned)(m3 >> 32);
    }
}

// ---------------- final: last enc term + 2-layer MLP ----------------
__global__ __launch_bounds__(512) void final_kernel(
    const int* __restrict__ t_index, const unsigned* __restrict__ sb_last,
    const float* __restrict__ enc, const float* __restrict__ query,
    const float* __restrict__ W1, const float* __restrict__ b1,
    const float* __restrict__ W2, const float* __restrict__ b2,
    float* __restrict__ out, float klast)
{
    int tid = threadIdx.x;
    int row = tid >> 2;                          // 0..127 = b*K + k
    int p = tid & 3;                             // j-quarter
    int b = row >> 5;
    unsigned w = sb_last[t_index[row] * BB + b];
    float feat[2 * DD];
    #pragma unroll
    for (int i = 0; i < DD; ++i)
        feat[i] = enc[row * DD + i] + klast * (float)((w >> i) & 1u);
    #pragma unroll
    for (int i = 0; i < DD; ++i)
        feat[DD + i] = query[b * DD + i];
    float acc = 0.0f;
    for (int jj = 0; jj < 16; ++jj) {
        int j = p * 16 + jj;
        float h = b1[j];
        #pragma unroll
        for (int i = 0; i < 2 * DD; ++i)
            h += feat[i] * W1[j * 2 * DD + i];
        acc += W2[j] * fmaxf(h, 0.0f);
    }
    acc += __shfl_down(acc, 1, 4);
    acc += __shfl_down(acc, 2, 4);
    if (p == 0) out[row] = acc + b2[0];
}

extern "C" void kernel_launch(void* const* d_in, const int* in_sizes, int n_in,
                              void* d_out, int out_size, void* d_ws, size_t ws_size,
                              hipStream_t stream)
{
    const int*   edge_src  = (const int*)d_in[0];
    const int*   edge_dst  = (const int*)d_in[1];
    const int*   edge_type = (const int*)d_in[2];
    const int*   h_index   = (const int*)d_in[3];
    const int*   t_index   = (const int*)d_in[4];
    const int*   r_index   = (const int*)d_in[5];
    const float* query_emb = (const float*)d_in[6];
    const float* relw_W    = (const float*)d_in[7];
    const float* relw_b    = (const float*)d_in[8];
    const float* lin_W     = (const float*)d_in[9];
    const float* lin_b     = (const float*)d_in[10];
    const float* mlp_W1    = (const float*)d_in[11];
    const float* mlp_b1    = (const float*)d_in[12];
    const float* mlp_W2    = (const float*)d_in[13];
    const float* mlp_b2    = (const float*)d_in[14];
    float* out = (float*)d_out;

    // workspace layout (4-byte units)
    float*    v       = (float*)d_ws;                 // N*D*B = 2,560,000
    float*    c       = v + NN * BB * DD;             // 2,560,000
    unsigned* sb0     = (unsigned*)(c + NN * BB * DD);// 80,000
    unsigned* sb1     = sb0 + NN * BB;                // 80,000
    float*    w_rel   = (float*)(sb1 + NN * BB);      // 5,120
    float*    query   = w_rel + BB * DRR * DD;        // 128
    float*    enc     = query + BB * DD;              // 4,096
    int*      row_ptr = (int*)(enc + BB * KK * DD);   // 20,016 (padded)
    int*      cnt     = row_ptr + 20016;              // 20,000
    unsigned* col     = (unsigned*)(cnt + NN);        // 320,000

    // temporal kernel weights
    float r = 0.95f;
    float ns = (1.0f - powf(r, (float)TT)) / (1.0f - r);
    float kv[TT];
    float p = 1.0f;
    for (int t = 0; t < TT; ++t) { kv[t] = p / ns; p *= r; }

    prep_kernel<<<(BB * DRR * DD) / 256, 256, 0, stream>>>(
        r_index, query_emb, relw_W, relw_b, w_rel, query);
    zero_cnt_kernel<<<(NN + 255) / 256, 256, 0, stream>>>(cnt);
    init_kernel<<<(NN * BB * DD) / 256, 256, 0, stream>>>(h_index, query, v, c, sb0);
    seed_kernel<<<1, 128, 0, stream>>>(h_index, query, sb0);
    hist_kernel<<<(EE + 255) / 256, 256, 0, stream>>>(edge_dst, cnt);
    scan_kernel<<<1, 1024, 0, stream>>>(cnt, row_ptr);
    scatter_kernel<<<(EE + 255) / 256, 256, 0, stream>>>(
        edge_src, edge_dst, edge_type, row_ptr, cnt, col);

    unsigned* bufs[2] = {sb0, sb1};
    for (int t = 1; t < TT; ++t) {
        step_kernel<<<NN / NPB, THREADS, 0, stream>>>(
            row_ptr, col, bufs[(t - 1) & 1], bufs[t & 1], w_rel, lin_W, lin_b,
            v, c, t_index, enc, kv[t - 1], (t == 1) ? 1 : 0);
    }
    final_kernel<<<1, 512, 0, stream>>>(
        t_index, bufs[(TT - 1) & 1], enc, query, mlp_W1, mlp_b1, mlp_W2, mlp_b2,
        out, kv[TT - 1]);
}